// Round 11
// baseline (205.807 us; speedup 1.0000x reference)
//
#include <hip/hip_runtime.h>
#include <hip/hip_bf16.h>
#include <math.h>

// Problem constants (from reference)
#define B_ROWS 4096
#define C_ROWS 2048
#define D_DIM  2048
#define NUM 2
#define MAX_ITER 15
#define NEAREST 3
#define MARGIN 1.0f

typedef __bf16 bf16_t;
typedef bf16_t bf16x8 __attribute__((ext_vector_type(8)));
typedef float f32x4 __attribute__((ext_vector_type(4)));

// ---------------------------------------------------------------------------
// conv: one wave per row, f32 -> bf16 (16B stores) + row sumsq via shuffle.
// Rows [0,4096) = feature, [4096,6144) = centers. 4 waves/block.
// Block 0 zero-inits out (select accumulates onto it; stream order).
// ---------------------------------------------------------------------------
__global__ __launch_bounds__(256) void conv_rows(const float* __restrict__ F,
                                                 const float* __restrict__ Cn,
                                                 bf16_t* __restrict__ Fb,
                                                 bf16_t* __restrict__ Cb,
                                                 float* __restrict__ f2,
                                                 float* __restrict__ c2,
                                                 float* __restrict__ out) {
    if (blockIdx.x == 0 && threadIdx.x == 0) out[0] = 0.0f;
    int wave = threadIdx.x >> 6;
    int lane = threadIdx.x & 63;
    int row = blockIdx.x * 4 + wave;          // 0..6143
    const float* p; bf16_t* q; float* sq; int r;
    if (row < B_ROWS) {
        r = row; p = F + (size_t)r * D_DIM; q = Fb + (size_t)r * D_DIM; sq = f2;
    } else {
        r = row - B_ROWS; p = Cn + (size_t)r * D_DIM; q = Cb + (size_t)r * D_DIM; sq = c2;
    }
    float s = 0.0f;
    #pragma unroll
    for (int it = 0; it < 4; ++it) {
        int k = (it * 64 + lane) * 8;         // 8 consecutive floats per lane
        float4 v0 = *(const float4*)(p + k);
        float4 v1 = *(const float4*)(p + k + 4);
        s += v0.x * v0.x + v0.y * v0.y + v0.z * v0.z + v0.w * v0.w;
        s += v1.x * v1.x + v1.y * v1.y + v1.z * v1.z + v1.w * v1.w;
        bf16x8 b;
        b[0] = (bf16_t)v0.x; b[1] = (bf16_t)v0.y; b[2] = (bf16_t)v0.z; b[3] = (bf16_t)v0.w;
        b[4] = (bf16_t)v1.x; b[5] = (bf16_t)v1.y; b[6] = (bf16_t)v1.z; b[7] = (bf16_t)v1.w;
        *(bf16x8*)(q + k) = b;
    }
    #pragma unroll
    for (int off = 32; off >= 1; off >>= 1) s += __shfl_down(s, off);
    if (lane == 0) sq[r] = s;
}

// ---------------------------------------------------------------------------
// Fused bf16 MFMA distance GEMM (Dfc and Dcc in one dispatch).
// BK=64 as two split K-panels (R8 win), NOW with FRAGMENT-ORDERED STAGING:
// the LDS side of global_load_lds is fixed at base+lane*16B, but the global
// source is per-lane free. Each staging instruction loads one 16x32 MFMA
// operand sub-tile in exactly fragment order:
//   lane l <- global(row s*16 + (l&15), col k0 + h*32 + (l>>4)*8)
// so fragment reads are As[h][subtile*512 + lane*8] — stride-1, ZERO bank
// conflicts (previous row-major layout was structurally 8-way conflicted:
// 6.3e6 SQ_LDS_BANK_CONFLICT/dispatch).
// PITFALL (R7): never use nonzero imm offset on global_load_lds.
// 128x128 tile, 4 waves (2x2 of 64x64), 16x16x32 MFMA.
//   Out[m][n] = bf16( a2[m] + c2[n] - 2 * sum_k A[m][k]*Cb[n][k] )
// ---------------------------------------------------------------------------
__global__ __launch_bounds__(256, 3) void gemm_d2_fused(const bf16_t* __restrict__ Fb,
                                                        const bf16_t* __restrict__ Cb,
                                                        const float* __restrict__ f2,
                                                        const float* __restrict__ c2,
                                                        bf16_t* __restrict__ Dfc,
                                                        bf16_t* __restrict__ Dcc) {
    // [panel][subtile(8)][512 elems]; subtile = 16 rows x 32 cols in frag order
    __shared__ __align__(16) bf16_t As[2][8 * 512];
    __shared__ __align__(16) bf16_t Bs[2][8 * 512];

    const int tid  = threadIdx.x;
    const int wave = tid >> 6;
    const int lane = tid & 63;

    const int by = blockIdx.y;
    const bf16_t* A; const float* a2v; bf16_t* Out; int bm;
    if (by < B_ROWS / 128) { A = Fb; a2v = f2; Out = Dfc; bm = by * 128; }
    else { A = Cb; a2v = c2; Out = Dcc; bm = (by - B_ROWS / 128) * 128; }
    const int bn = blockIdx.x * 128;
    const int N = C_ROWS, K = D_DIM;

    const int wm = (wave >> 1) * 64;       // wave row offset
    const int wn = (wave & 1) * 64;        // wave col offset
    const int sa = (wave >> 1) * 4;        // A subtile base for this wave
    const int sb = (wave & 1) * 4;         // B subtile base

    f32x4 acc[4][4] = {};

    // fragment-order lane offsets (shared by staging source and MFMA read)
    const int fr = lane & 15;              // fragment row 0..15
    const int fk = (lane >> 4) * 8;        // fragment k offset 0,8,16,24
    const int laneA = fr * K + fk;         // per-lane global element offset

    for (int k0 = 0; k0 < K; k0 += 64) {
        // Wave w stages subtiles s = 2w, 2w+1 for A and B, both panels.
        #pragma unroll
        for (int t = 0; t < 2; ++t) {
            int s = wave * 2 + t;          // subtile 0..7 (16 rows each)
            const bf16_t* gA0 = A  + (size_t)((bm + s * 16) * K + k0) + laneA;
            const bf16_t* gB0 = Cb + (size_t)((bn + s * 16) * K + k0) + laneA;
            __builtin_amdgcn_global_load_lds(
                (const __attribute__((address_space(1))) void*)gA0,
                (__attribute__((address_space(3))) void*)&As[0][s * 512], 16, 0, 0);
            __builtin_amdgcn_global_load_lds(
                (const __attribute__((address_space(1))) void*)gB0,
                (__attribute__((address_space(3))) void*)&Bs[0][s * 512], 16, 0, 0);
            __builtin_amdgcn_global_load_lds(
                (const __attribute__((address_space(1))) void*)(gA0 + 32),
                (__attribute__((address_space(3))) void*)&As[1][s * 512], 16, 0, 0);
            __builtin_amdgcn_global_load_lds(
                (const __attribute__((address_space(1))) void*)(gB0 + 32),
                (__attribute__((address_space(3))) void*)&Bs[1][s * 512], 16, 0, 0);
        }
        __syncthreads();

        #pragma unroll
        for (int h = 0; h < 2; ++h) {
            bf16x8 af[4], bf_[4];
            #pragma unroll
            for (int i = 0; i < 4; ++i) {
                af[i]  = *(const bf16x8*)&As[h][(sa + i) * 512 + lane * 8];
                bf_[i] = *(const bf16x8*)&Bs[h][(sb + i) * 512 + lane * 8];
            }
            #pragma unroll
            for (int i = 0; i < 4; ++i)
                #pragma unroll
                for (int j = 0; j < 4; ++j)
                    acc[i][j] = __builtin_amdgcn_mfma_f32_16x16x32_bf16(af[i], bf_[j], acc[i][j], 0, 0, 0);
        }
        __syncthreads();
    }

    // Epilogue: d2 = a2[m] + c2[n] - 2*dot, stored bf16.
    // C/D: col=lane&15, row=(lane>>4)*4+reg
    const int ncol = lane & 15;
    const int r4   = (lane >> 4) * 4;
    #pragma unroll
    for (int i = 0; i < 4; ++i) {
        #pragma unroll
        for (int r = 0; r < 4; ++r) {
            int m = bm + wm + i * 16 + r4 + r;
            float am = a2v[m];
            #pragma unroll
            for (int j = 0; j < 4; ++j) {
                int n = bn + wn + j * 16 + ncol;
                Out[(size_t)m * N + n] = (bf16_t)(am + c2[n] - 2.0f * acc[i][j][r]);
            }
        }
    }
}

// ---------------------------------------------------------------------------
// select v3: bf16 distance rows, vectorized 16B loads.
// Iterative argmin w/ exclusion over Dfc row; on-demand trust from Dcc:
//   label in near3[sel]  <=>  #{ j : (Dcc[sel][j], j) <lex (Dcc[sel][label],
//   label) } < NEAREST   (stable argsort -> lexicographic order)
// Ownership: lane l, group g, sub e: n = g*512 + l*8 + e; excl bit g*8+e.
// 4 waves/block, one row per wave; one atomicAdd per block onto out.
// ---------------------------------------------------------------------------
__global__ __launch_bounds__(256) void select_kernel(const bf16_t* __restrict__ Dfc,
                                                     const bf16_t* __restrict__ Dcc,
                                                     float* __restrict__ out, int C) {
    int wave = threadIdx.x >> 6, lane = threadIdx.x & 63;
    int b = blockIdx.x * 4 + wave;
    int label = b / NUM;
    const bf16_t* row = Dfc + (size_t)b * C;

    float vals[32];
    #pragma unroll
    for (int g = 0; g < 4; ++g) {
        bf16x8 v = *(const bf16x8*)(row + g * 512 + lane * 8);
        #pragma unroll
        for (int e = 0; e < 8; ++e) {
            int n = g * 512 + lane * 8 + e;
            float f = (float)v[e];
            vals[g * 8 + e] = (n == label) ? INFINITY : f;
        }
    }

    unsigned int excl = 0;
    float min_diff = 0.0f;
    int found = 0;
    for (int it = 0; it < MAX_ITER; ++it) {
        float bestv = INFINITY; int bestidx = 0x7fffffff;
        #pragma unroll
        for (int g = 0; g < 4; ++g)
            #pragma unroll
            for (int e = 0; e < 8; ++e) {
                int bit = g * 8 + e;
                if (excl & (1u << bit)) continue;
                float v = vals[bit];
                int idx = g * 512 + lane * 8 + e;
                if (v < bestv || (v == bestv && idx < bestidx)) { bestv = v; bestidx = idx; }
            }
        for (int off = 32; off >= 1; off >>= 1) {
            float ov = __shfl_down(bestv, off); int oi = __shfl_down(bestidx, off);
            if (ov < bestv || (ov == bestv && oi < bestidx)) { bestv = ov; bestidx = oi; }
        }
        int sel = __shfl(bestidx, 0);
        float selv = __shfl(bestv, 0);

        // --- on-demand trust: count lex-smaller entries of Dcc row sel ---
        const bf16_t* crow = Dcc + (size_t)sel * C;
        float dl = (float)crow[label];          // uniform address: broadcast
        int cnt = 0;
        #pragma unroll
        for (int g = 0; g < 4; ++g) {
            bf16x8 v = *(const bf16x8*)(crow + g * 512 + lane * 8);
            #pragma unroll
            for (int e = 0; e < 8; ++e) {
                int idx = g * 512 + lane * 8 + e;
                float f = (float)v[e];
                cnt += (f < dl || (f == dl && idx < label)) ? 1 : 0;
            }
        }
        #pragma unroll
        for (int off = 32; off >= 1; off >>= 1) cnt += __shfl_down(cnt, off);
        cnt = __shfl(cnt, 0);
        bool trusted = (cnt >= NEAREST);

        if (trusted) { min_diff = sqrtf(fmaxf(selv, 0.0f)); found = 1; break; }
        if (((sel >> 3) & 63) == lane) excl |= 1u << (((sel >> 9) << 3) | (sel & 7));
    }
    __shared__ float hs[4];
    if (lane == 0) {
        float same = sqrtf(fmaxf((float)row[label], 0.0f));
        float md = found ? min_diff : 0.0f;
        hs[wave] = fmaxf(MARGIN + same - md, 0.0f);
    }
    __syncthreads();
    if (threadIdx.x == 0)
        atomicAdd(out, (hs[0] + hs[1] + hs[2] + hs[3]) * (1.0f / (float)B_ROWS));
}

// ---------------------------------------------------------------------------
extern "C" void kernel_launch(void* const* d_in, const int* in_sizes, int n_in,
                              void* d_out, int out_size, void* d_ws, size_t ws_size,
                              hipStream_t stream) {
    const float* feature = (const float*)d_in[0];  // 4096 x 2048
    const float* centers = (const float*)d_in[1];  // 2048 x 2048
    float* out = (float*)d_out;                    // scalar

    // Workspace layout (Dfc/Dcc bf16)
    bf16_t* Dfc  = (bf16_t*)d_ws;                            // 4096*2048 bf16
    bf16_t* Dcc  = Dfc + (size_t)B_ROWS * C_ROWS;            // 2048*2048 bf16
    bf16_t* Fbf  = Dcc + (size_t)C_ROWS * C_ROWS;            // 4096*2048 bf16
    bf16_t* Cbf  = Fbf + (size_t)B_ROWS * D_DIM;             // 2048*2048 bf16
    float*  f2   = (float*)(Cbf + (size_t)C_ROWS * D_DIM);   // 4096
    float*  c2   = f2 + B_ROWS;                              // 2048

    conv_rows<<<(B_ROWS + C_ROWS) / 4, 256, 0, stream>>>(feature, centers, Fbf, Cbf,
                                                         f2, c2, out);

    // Both distance matrices in one dispatch: grid (16, 32+16) = 768 blocks.
    gemm_d2_fused<<<dim3(C_ROWS / 128, B_ROWS / 128 + C_ROWS / 128), 256, 0, stream>>>(
        Fbf, Cbf, f2, c2, Dfc, Dcc);

    // select with on-demand trust (reads Dcc directly; no near3 dispatch).
    select_kernel<<<B_ROWS / 4, 256, 0, stream>>>(Dfc, Dcc, out, C_ROWS);
}

// Round 12
// 159.206 us; speedup vs baseline: 1.2927x; 1.2927x over previous
//
#include <hip/hip_runtime.h>
#include <hip/hip_bf16.h>
#include <math.h>

// Problem constants (from reference)
#define B_ROWS 4096
#define C_ROWS 2048
#define D_DIM  2048
#define NUM 2
#define MAX_ITER 15
#define NEAREST 3
#define MARGIN 1.0f

typedef __bf16 bf16_t;
typedef bf16_t bf16x8 __attribute__((ext_vector_type(8)));
typedef float f32x4 __attribute__((ext_vector_type(4)));

// ---------------------------------------------------------------------------
// conv: one wave per row, f32 -> bf16 (16B stores) + row sumsq via shuffle.
// Rows [0,4096) = feature, [4096,6144) = centers. 4 waves/block.
// Block 0 zero-inits out (select accumulates onto it; stream order).
// ---------------------------------------------------------------------------
__global__ __launch_bounds__(256) void conv_rows(const float* __restrict__ F,
                                                 const float* __restrict__ Cn,
                                                 bf16_t* __restrict__ Fb,
                                                 bf16_t* __restrict__ Cb,
                                                 float* __restrict__ f2,
                                                 float* __restrict__ c2,
                                                 float* __restrict__ out) {
    if (blockIdx.x == 0 && threadIdx.x == 0) out[0] = 0.0f;
    int wave = threadIdx.x >> 6;
    int lane = threadIdx.x & 63;
    int row = blockIdx.x * 4 + wave;          // 0..6143
    const float* p; bf16_t* q; float* sq; int r;
    if (row < B_ROWS) {
        r = row; p = F + (size_t)r * D_DIM; q = Fb + (size_t)r * D_DIM; sq = f2;
    } else {
        r = row - B_ROWS; p = Cn + (size_t)r * D_DIM; q = Cb + (size_t)r * D_DIM; sq = c2;
    }
    float s = 0.0f;
    #pragma unroll
    for (int it = 0; it < 4; ++it) {
        int k = (it * 64 + lane) * 8;         // 8 consecutive floats per lane
        float4 v0 = *(const float4*)(p + k);
        float4 v1 = *(const float4*)(p + k + 4);
        s += v0.x * v0.x + v0.y * v0.y + v0.z * v0.z + v0.w * v0.w;
        s += v1.x * v1.x + v1.y * v1.y + v1.z * v1.z + v1.w * v1.w;
        bf16x8 b;
        b[0] = (bf16_t)v0.x; b[1] = (bf16_t)v0.y; b[2] = (bf16_t)v0.z; b[3] = (bf16_t)v0.w;
        b[4] = (bf16_t)v1.x; b[5] = (bf16_t)v1.y; b[6] = (bf16_t)v1.z; b[7] = (bf16_t)v1.w;
        *(bf16x8*)(q + k) = b;
    }
    #pragma unroll
    for (int off = 32; off >= 1; off >>= 1) s += __shfl_down(s, off);
    if (lane == 0) sq[r] = s;
}

// ---------------------------------------------------------------------------
// Fused bf16 MFMA distance GEMM (Dfc and Dcc in one dispatch). R10 config —
// the measured optimum of this structure (64us, 805 TF, MfmaUtil 32%).
// BK=64 as two split row-major [128][32] K-panels (R8: halves barrier drains
// at the fast 64B LDS banking).
// MEASURED PITFALLS (do not revisit):
//  - R5: single [128][64] layout -> 128B row stride triples bank conflicts.
//  - R7: global_load_lds imm offset != 0 corrupts the transfer; always bake
//    displacement into the pointer (gA0 + 32).
//  - R11: "fragment-ordered" staging (per-lane row-strided global sources)
//    zeroes LDS conflicts but breaks consecutive-lane coalescing -> ~4x VMEM
//    transactions, GEMM 64->112us. Under global_load_lds, coalesced global
//    reads and conflict-free LDS fragment reads are mutually exclusive; the
//    8-way read conflict is the cheaper evil.
// 128x128 tile, 4 waves (2x2 of 64x64), 16x16x32 MFMA.
//   Out[m][n] = bf16( a2[m] + c2[n] - 2 * sum_k A[m][k]*Cb[n][k] )
// ---------------------------------------------------------------------------
__global__ __launch_bounds__(256, 3) void gemm_d2_fused(const bf16_t* __restrict__ Fb,
                                                        const bf16_t* __restrict__ Cb,
                                                        const float* __restrict__ f2,
                                                        const float* __restrict__ c2,
                                                        bf16_t* __restrict__ Dfc,
                                                        bf16_t* __restrict__ Dcc) {
    __shared__ __align__(16) bf16_t As[2][128 * 32];
    __shared__ __align__(16) bf16_t Bs[2][128 * 32];

    const int tid  = threadIdx.x;
    const int wave = tid >> 6;
    const int lane = tid & 63;

    const int by = blockIdx.y;
    const bf16_t* A; const float* a2v; bf16_t* Out; int bm;
    if (by < B_ROWS / 128) { A = Fb; a2v = f2; Out = Dfc; bm = by * 128; }
    else { A = Cb; a2v = c2; Out = Dcc; bm = (by - B_ROWS / 128) * 128; }
    const int bn = blockIdx.x * 128;
    const int N = C_ROWS, K = D_DIM;

    const int wm = (wave >> 1) * 64;
    const int wn = (wave & 1) * 64;

    f32x4 acc[4][4] = {};

    const int c0   = wave * 2;
    const int rsub = lane >> 2;           // 0..15
    const int ksub = (lane & 3) * 8;      // 0,8,16,24 (16B)
    const int mrow = lane & 15;
    const int kq   = (lane >> 4) * 8;

    for (int k0 = 0; k0 < K; k0 += 64) {
        #pragma unroll
        for (int is = 0; is < 2; ++is) {
            int chunk = c0 + is;
            int row = chunk * 16 + rsub;
            const bf16_t* gA0 = A  + (size_t)(bm + row) * K + (k0 + ksub);
            const bf16_t* gB0 = Cb + (size_t)(bn + row) * K + (k0 + ksub);
            const bf16_t* gA1 = gA0 + 32;   // k0 + [32,64)
            const bf16_t* gB1 = gB0 + 32;
            __builtin_amdgcn_global_load_lds(
                (const __attribute__((address_space(1))) void*)gA0,
                (__attribute__((address_space(3))) void*)&As[0][chunk * 512], 16, 0, 0);
            __builtin_amdgcn_global_load_lds(
                (const __attribute__((address_space(1))) void*)gB0,
                (__attribute__((address_space(3))) void*)&Bs[0][chunk * 512], 16, 0, 0);
            __builtin_amdgcn_global_load_lds(
                (const __attribute__((address_space(1))) void*)gA1,
                (__attribute__((address_space(3))) void*)&As[1][chunk * 512], 16, 0, 0);
            __builtin_amdgcn_global_load_lds(
                (const __attribute__((address_space(1))) void*)gB1,
                (__attribute__((address_space(3))) void*)&Bs[1][chunk * 512], 16, 0, 0);
        }
        __syncthreads();

        #pragma unroll
        for (int h = 0; h < 2; ++h) {
            bf16x8 af[4], bf_[4];
            #pragma unroll
            for (int i = 0; i < 4; ++i) {
                af[i]  = *(const bf16x8*)&As[h][(wm + i * 16 + mrow) * 32 + kq];
                bf_[i] = *(const bf16x8*)&Bs[h][(wn + i * 16 + mrow) * 32 + kq];
            }
            #pragma unroll
            for (int i = 0; i < 4; ++i)
                #pragma unroll
                for (int j = 0; j < 4; ++j)
                    acc[i][j] = __builtin_amdgcn_mfma_f32_16x16x32_bf16(af[i], bf_[j], acc[i][j], 0, 0, 0);
        }
        __syncthreads();
    }

    // Epilogue: d2 = a2[m] + c2[n] - 2*dot, stored bf16.
    // C/D: col=lane&15, row=(lane>>4)*4+reg
    const int ncol = lane & 15;
    const int r4   = (lane >> 4) * 4;
    #pragma unroll
    for (int i = 0; i < 4; ++i) {
        #pragma unroll
        for (int r = 0; r < 4; ++r) {
            int m = bm + wm + i * 16 + r4 + r;
            float am = a2v[m];
            #pragma unroll
            for (int j = 0; j < 4; ++j) {
                int n = bn + wn + j * 16 + ncol;
                Out[(size_t)m * N + n] = (bf16_t)(am + c2[n] - 2.0f * acc[i][j][r]);
            }
        }
    }
}

// ---------------------------------------------------------------------------
// select v3: bf16 distance rows, vectorized 16B loads.
// Iterative argmin w/ exclusion over Dfc row; on-demand trust from Dcc:
//   label in near3[sel]  <=>  #{ j : (Dcc[sel][j], j) <lex (Dcc[sel][label],
//   label) } < NEAREST   (stable argsort -> lexicographic order)
// Ownership: lane l, group g, sub e: n = g*512 + l*8 + e; excl bit g*8+e.
// 4 waves/block, one row per wave; one atomicAdd per block onto out.
// ---------------------------------------------------------------------------
__global__ __launch_bounds__(256) void select_kernel(const bf16_t* __restrict__ Dfc,
                                                     const bf16_t* __restrict__ Dcc,
                                                     float* __restrict__ out, int C) {
    int wave = threadIdx.x >> 6, lane = threadIdx.x & 63;
    int b = blockIdx.x * 4 + wave;
    int label = b / NUM;
    const bf16_t* row = Dfc + (size_t)b * C;

    float vals[32];
    #pragma unroll
    for (int g = 0; g < 4; ++g) {
        bf16x8 v = *(const bf16x8*)(row + g * 512 + lane * 8);
        #pragma unroll
        for (int e = 0; e < 8; ++e) {
            int n = g * 512 + lane * 8 + e;
            float f = (float)v[e];
            vals[g * 8 + e] = (n == label) ? INFINITY : f;
        }
    }

    unsigned int excl = 0;
    float min_diff = 0.0f;
    int found = 0;
    for (int it = 0; it < MAX_ITER; ++it) {
        float bestv = INFINITY; int bestidx = 0x7fffffff;
        #pragma unroll
        for (int g = 0; g < 4; ++g)
            #pragma unroll
            for (int e = 0; e < 8; ++e) {
                int bit = g * 8 + e;
                if (excl & (1u << bit)) continue;
                float v = vals[bit];
                int idx = g * 512 + lane * 8 + e;
                if (v < bestv || (v == bestv && idx < bestidx)) { bestv = v; bestidx = idx; }
            }
        for (int off = 32; off >= 1; off >>= 1) {
            float ov = __shfl_down(bestv, off); int oi = __shfl_down(bestidx, off);
            if (ov < bestv || (ov == bestv && oi < bestidx)) { bestv = ov; bestidx = oi; }
        }
        int sel = __shfl(bestidx, 0);
        float selv = __shfl(bestv, 0);

        // --- on-demand trust: count lex-smaller entries of Dcc row sel ---
        const bf16_t* crow = Dcc + (size_t)sel * C;
        float dl = (float)crow[label];          // uniform address: broadcast
        int cnt = 0;
        #pragma unroll
        for (int g = 0; g < 4; ++g) {
            bf16x8 v = *(const bf16x8*)(crow + g * 512 + lane * 8);
            #pragma unroll
            for (int e = 0; e < 8; ++e) {
                int idx = g * 512 + lane * 8 + e;
                float f = (float)v[e];
                cnt += (f < dl || (f == dl && idx < label)) ? 1 : 0;
            }
        }
        #pragma unroll
        for (int off = 32; off >= 1; off >>= 1) cnt += __shfl_down(cnt, off);
        cnt = __shfl(cnt, 0);
        bool trusted = (cnt >= NEAREST);

        if (trusted) { min_diff = sqrtf(fmaxf(selv, 0.0f)); found = 1; break; }
        if (((sel >> 3) & 63) == lane) excl |= 1u << (((sel >> 9) << 3) | (sel & 7));
    }
    __shared__ float hs[4];
    if (lane == 0) {
        float same = sqrtf(fmaxf((float)row[label], 0.0f));
        float md = found ? min_diff : 0.0f;
        hs[wave] = fmaxf(MARGIN + same - md, 0.0f);
    }
    __syncthreads();
    if (threadIdx.x == 0)
        atomicAdd(out, (hs[0] + hs[1] + hs[2] + hs[3]) * (1.0f / (float)B_ROWS));
}

// ---------------------------------------------------------------------------
extern "C" void kernel_launch(void* const* d_in, const int* in_sizes, int n_in,
                              void* d_out, int out_size, void* d_ws, size_t ws_size,
                              hipStream_t stream) {
    const float* feature = (const float*)d_in[0];  // 4096 x 2048
    const float* centers = (const float*)d_in[1];  // 2048 x 2048
    float* out = (float*)d_out;                    // scalar

    // Workspace layout (Dfc/Dcc bf16)
    bf16_t* Dfc  = (bf16_t*)d_ws;                            // 4096*2048 bf16
    bf16_t* Dcc  = Dfc + (size_t)B_ROWS * C_ROWS;            // 2048*2048 bf16
    bf16_t* Fbf  = Dcc + (size_t)C_ROWS * C_ROWS;            // 4096*2048 bf16
    bf16_t* Cbf  = Fbf + (size_t)B_ROWS * D_DIM;             // 2048*2048 bf16
    float*  f2   = (float*)(Cbf + (size_t)C_ROWS * D_DIM);   // 4096
    float*  c2   = f2 + B_ROWS;                              // 2048

    conv_rows<<<(B_ROWS + C_ROWS) / 4, 256, 0, stream>>>(feature, centers, Fbf, Cbf,
                                                         f2, c2, out);

    // Both distance matrices in one dispatch: grid (16, 32+16) = 768 blocks.
    gemm_d2_fused<<<dim3(C_ROWS / 128, B_ROWS / 128 + C_ROWS / 128), 256, 0, stream>>>(
        Fbf, Cbf, f2, c2, Dfc, Dcc);

    // select with on-demand trust (reads Dcc directly; no near3 dispatch).
    select_kernel<<<B_ROWS / 4, 256, 0, stream>>>(Dfc, Dcc, out, C_ROWS);
}